// Round 5
// baseline (558.249 us; speedup 1.0000x reference)
//
#include <hip/hip_runtime.h>

#define NH 4
#define HD 128
#define BS 32
#define STRIDE 16

typedef float  floatx4 __attribute__((ext_vector_type(4)));
typedef __bf16 bf16x8  __attribute__((ext_vector_type(8)));
typedef __bf16 bf16x2  __attribute__((ext_vector_type(2)));
typedef unsigned short u16x8 __attribute__((ext_vector_type(8)));

__device__ __forceinline__ unsigned short f2bf(float f) {
  unsigned u = __builtin_bit_cast(unsigned, f);
  u += 0x7FFFu + ((u >> 16) & 1u);   // RTNE (inputs finite)
  return (unsigned short)(u >> 16);
}

__device__ __forceinline__ bf16x8 cvt8(float4 lo, float4 hi) {
  bf16x8 r;
#if __has_builtin(__builtin_amdgcn_cvt_pk_bf16_f32)
  bf16x2 p0 = __builtin_bit_cast(bf16x2, __builtin_amdgcn_cvt_pk_bf16_f32(lo.x, lo.y));
  bf16x2 p1 = __builtin_bit_cast(bf16x2, __builtin_amdgcn_cvt_pk_bf16_f32(lo.z, lo.w));
  bf16x2 p2 = __builtin_bit_cast(bf16x2, __builtin_amdgcn_cvt_pk_bf16_f32(hi.x, hi.y));
  bf16x2 p3 = __builtin_bit_cast(bf16x2, __builtin_amdgcn_cvt_pk_bf16_f32(hi.z, hi.w));
  r[0] = p0[0]; r[1] = p0[1]; r[2] = p1[0]; r[3] = p1[1];
  r[4] = p2[0]; r[5] = p2[1]; r[6] = p3[0]; r[7] = p3[1];
#else
  u16x8 t;
  t[0] = f2bf(lo.x); t[1] = f2bf(lo.y); t[2] = f2bf(lo.z); t[3] = f2bf(lo.w);
  t[4] = f2bf(hi.x); t[5] = f2bf(hi.y); t[6] = f2bf(hi.z); t[7] = f2bf(hi.w);
  r = __builtin_bit_cast(bf16x8, t);
#endif
  return r;
}

// Prep: LDS-tiled transpose of w into wt layout [mat][j][k0][fq][e][dq] (bf16).
// Block 256 (last) writes the cu_out prefix tail.
__global__ void prep_kernel(const float* __restrict__ wk, const float* __restrict__ wv,
                            unsigned short* __restrict__ wt,
                            const int* __restrict__ cu, int num_seqs,
                            float* __restrict__ tail) {
  const int bx = blockIdx.x;
  if (bx == 2 * BS * 4) {
    if (threadIdx.x == 0) {
      int acc = 0;
      tail[0] = 0.0f;
      for (int b = 0; b < num_seqs; ++b) {
        int n = cu[b + 1] - cu[b];
        acc += (n - BS) / STRIDE;
        tail[b + 1] = (float)acc;
      }
    }
    return;
  }
  const int mat = bx >> 7;
  const int j   = (bx >> 2) & 31;
  const int k0  = bx & 3;
  const float* __restrict__ w =
      (mat ? wv : wk) + (size_t)j * (HD * HD) + (size_t)k0 * 32 * HD;
  __shared__ unsigned short tile[32][HD];
  const int t = threadIdx.x;
  const int r = t >> 3, c = (t & 7) * 16;
#pragma unroll
  for (int i = 0; i < 16; i += 4) {
    float4 f = *(const float4*)(w + r * HD + c + i);
    tile[r][c + i + 0] = f2bf(f.x);
    tile[r][c + i + 1] = f2bf(f.y);
    tile[r][c + i + 2] = f2bf(f.z);
    tile[r][c + i + 3] = f2bf(f.w);
  }
  __syncthreads();
  unsigned short* dst =
      wt + (size_t)mat * (BS * HD * HD) + (size_t)j * 16384 + k0 * 4096;
#pragma unroll
  for (int it = 0; it < 2; ++it) {
    int fi = t + it * 256;      // 0..511 over (fq, e)
    int fq = fi >> 7, e = fi & 127;
    u16x8 fr;
#pragma unroll
    for (int dq = 0; dq < 8; ++dq) fr[dq] = tile[fq * 8 + dq][e];
    *(u16x8*)(dst + fq * 1024 + e * 8) = fr;
  }
}

// Main GEMM, v6: self-paced waves. NO LDS, NO barriers, no inline-asm waits.
// Wave = 16m x 64n; block = 4 waves = 32m x 128n; 1020 blocks, 2 blocks/CU.
// A and B both in explicit parity-2 REGISTER rings (prefetch distance = 2
// j-steps). Compiler emits precise per-register vmcnt waits (no LDS-DMA
// hazard to force conservative drains); sched_barrier(0) at each step top
// prevents loads sinking across steps (the v4 failure). A slow load stalls
// only its own wave -> stalls decorrelate across the CU's 8 waves.
// K-order (j asc, k0 asc) identical -> bit-identical output.
__global__ __launch_bounds__(256, 2) void kvc_gemm(
    const float* __restrict__ kp, const float* __restrict__ vp,
    const unsigned short* __restrict__ wt, const int* __restrict__ cu,
    float* __restrict__ out, long out_half, int M_total, int num_seqs) {

  const int mat = blockIdx.y;
  const float* __restrict__ x = mat ? vp : kp;
  const unsigned short* __restrict__ wmat = wt + (size_t)mat * (BS * HD * HD);
  float* __restrict__ outp = out + (size_t)mat * out_half;

  const int tid = threadIdx.x, wid = tid >> 6, lane = tid & 63;
  const int fl = lane & 15, fq = lane >> 4;
  const int mw = wid & 1;         // m-half within block
  const int nh = wid >> 1;        // n-half within block
  const int e0 = nh * 64;
  const int mbase = blockIdx.x * 32 + mw * 16;

  // Per-lane token base for this wave's 16-row m-fragment.
  int m = mbase + fl;
  int mc = m < M_total ? m : M_total - 1;
  int o = mc >> 2, h = mc & 3;
  int tb = 0, accb = 0;
  for (int b = 0; b < num_seqs; ++b) {
    int c0 = cu[b], c1 = cu[b + 1];
    int ol = (c1 - c0 - BS) / STRIDE;
    if (o >= accb && o - accb < ol) tb = c0 + (o - accb) * STRIDE;
    accb += ol;
  }
  const float* __restrict__ arow = x + ((size_t)tb * NH + h) * HD + fq * 8;
  const unsigned short* __restrict__ brow = wmat + fq * 1024 + (size_t)(e0 + fl) * 8;

  floatx4 acc[4];
#pragma unroll
  for (int ni = 0; ni < 4; ++ni) acc[ni] = (floatx4){0.f, 0.f, 0.f, 0.f};

  // Parity-2 register rings (named arrays, all indices compile-time).
  float4 a0[8], a1[8];
  bf16x8 b0[4][4], b1[4][4];

#define ALOADN(JN, A)                                                       \
  {                                                                         \
    const float* ar_ = arow + (size_t)(JN) * (NH * HD);                     \
    _Pragma("unroll") for (int k_ = 0; k_ < 4; ++k_) {                      \
      A[2 * k_]     = *(const float4*)(ar_ + k_ * 32);                      \
      A[2 * k_ + 1] = *(const float4*)(ar_ + k_ * 32 + 4);                  \
    }                                                                       \
  }

#define BLOADN(JN, B)                                                       \
  {                                                                         \
    const unsigned short* bp_ = brow + (size_t)(JN) * 16384;                \
    _Pragma("unroll") for (int k_ = 0; k_ < 4; ++k_)                        \
      _Pragma("unroll") for (int ni_ = 0; ni_ < 4; ++ni_)                   \
        B[k_][ni_] = *(const bf16x8*)(bp_ + k_ * 4096 + ni_ * 128);         \
  }

  // Step J consumes parity arrays (A,B) holding slice J, then refills them
  // with slice J+2 (clamped; redundant tail reloads are harmless: the
  // parity is dead afterwards). Loads placed after the MFMAs textually;
  // scheduler may interleave them upward (WAR-safe). sched_barrier(0)
  // at step top stops cross-step motion.
#define STEP(J, A, B)                                                       \
  {                                                                         \
    __builtin_amdgcn_sched_barrier(0);                                      \
    _Pragma("unroll") for (int k_ = 0; k_ < 4; ++k_) {                      \
      bf16x8 af_ = cvt8(A[2 * k_], A[2 * k_ + 1]);                          \
      _Pragma("unroll") for (int ni_ = 0; ni_ < 4; ++ni_)                   \
        acc[ni_] = __builtin_amdgcn_mfma_f32_16x16x32_bf16(                 \
            af_, B[k_][ni_], acc[ni_], 0, 0, 0);                            \
    }                                                                       \
    const int jn_ = ((J) + 2 < BS) ? (J) + 2 : BS - 1;                      \
    BLOADN(jn_, B);                                                         \
    ALOADN(jn_, A);                                                         \
  }

  // Prologue: slices 0 and 1 in flight.
  ALOADN(0, a0);
  BLOADN(0, b0);
  ALOADN(1, a1);
  BLOADN(1, b1);

  for (int j = 0; j < BS; j += 2) {
    STEP(j, a0, b0);
    STEP(j + 1, a1, b1);
  }

#undef STEP
#undef BLOADN
#undef ALOADN

  // C/D: col = fl (e offset within half), row = fq*4 + r.
#pragma unroll
  for (int ni = 0; ni < 4; ++ni) {
#pragma unroll
    for (int r = 0; r < 4; ++r) {
      const int mg = mbase + fq * 4 + r;
      if (mg < M_total)
        outp[(size_t)mg * HD + e0 + ni * 16 + fl] = acc[ni][r];
    }
  }
}

// Fallback path if ws is too small for the weight transpose.
__global__ void tail_kernel(const int* __restrict__ cu, int num_seqs,
                            float* __restrict__ tail) {
  if (threadIdx.x == 0) {
    int acc = 0;
    tail[0] = 0.0f;
    for (int b = 0; b < num_seqs; ++b) {
      int n = cu[b + 1] - cu[b];
      acc += (n - BS) / STRIDE;
      tail[b + 1] = (float)acc;
    }
  }
}

__global__ void kvc_naive(const float* __restrict__ kp, const float* __restrict__ vp,
                          const float* __restrict__ wk, const float* __restrict__ wv,
                          const int* __restrict__ cu, int num_seqs,
                          float* __restrict__ out, long out_half) {
  int o = blockIdx.x, h = blockIdx.y, mat = blockIdx.z;
  int e = threadIdx.x;
  int acc = 0, base = -1;
  for (int b = 0; b < num_seqs; ++b) {
    int n = cu[b + 1] - cu[b];
    int ol = (n - BS) / STRIDE;
    if (o < acc + ol) { base = cu[b] + (o - acc) * STRIDE; break; }
    acc += ol;
  }
  if (base < 0) return;
  const float* x = mat ? vp : kp;
  const float* w = mat ? wv : wk;
  float s = 0.f;
  for (int j = 0; j < BS; ++j)
    for (int d = 0; d < HD; ++d)
      s += x[(size_t)(base + j) * (NH * HD) + h * HD + d] * w[(j * HD + d) * HD + e];
  out[(size_t)mat * out_half + ((size_t)o * NH + h) * HD + e] = s;
}

extern "C" void kernel_launch(void* const* d_in, const int* in_sizes, int n_in,
                              void* d_out, int out_size, void* d_ws, size_t ws_size,
                              hipStream_t stream) {
  const float* kp = (const float*)d_in[0];
  const float* vp = (const float*)d_in[1];
  const float* wk = (const float*)d_in[2];
  const float* wv = (const float*)d_in[3];
  const int* cu = (const int*)d_in[4];
  const int num_seqs = in_sizes[4] - 1;
  float* out = (float*)d_out;

  const long total_out = ((long)out_size - (num_seqs + 1)) / (2L * NH * HD);
  const long out_half = total_out * NH * HD;
  const int M_total = (int)(total_out * NH);
  float* tail = out + 2 * out_half;

  const size_t need_ws = (size_t)2 * BS * HD * HD * sizeof(unsigned short);
  if (ws_size >= need_ws) {
    unsigned short* wt = (unsigned short*)d_ws;
    prep_kernel<<<2 * BS * 4 + 1, 256, 0, stream>>>(wk, wv, wt, cu, num_seqs, tail);
    dim3 grid((M_total + 31) / 32, 2);
    kvc_gemm<<<grid, 256, 0, stream>>>(kp, vp, wt, cu, out, out_half, M_total,
                                       num_seqs);
  } else {
    tail_kernel<<<1, 64, 0, stream>>>(cu, num_seqs, tail);
    dim3 grid((unsigned)total_out, NH, 2);
    kvc_naive<<<grid, HD, 0, stream>>>(kp, vp, wk, wv, cu, num_seqs, out, out_half);
  }
}

// Round 6
// 338.565 us; speedup vs baseline: 1.6489x; 1.6489x over previous
//
#include <hip/hip_runtime.h>

#define NH 4
#define HD 128
#define BS 32
#define STRIDE 16

typedef float  floatx4 __attribute__((ext_vector_type(4)));
typedef __bf16 bf16x8  __attribute__((ext_vector_type(8)));
typedef __bf16 bf16x2  __attribute__((ext_vector_type(2)));
typedef unsigned short u16x8 __attribute__((ext_vector_type(8)));

__device__ __forceinline__ unsigned short f2bf(float f) {
  unsigned u = __builtin_bit_cast(unsigned, f);
  u += 0x7FFFu + ((u >> 16) & 1u);   // RTNE (inputs finite)
  return (unsigned short)(u >> 16);
}

__device__ __forceinline__ bf16x8 cvt8(float4 lo, float4 hi) {
  bf16x8 r;
#if __has_builtin(__builtin_amdgcn_cvt_pk_bf16_f32)
  bf16x2 p0 = __builtin_bit_cast(bf16x2, __builtin_amdgcn_cvt_pk_bf16_f32(lo.x, lo.y));
  bf16x2 p1 = __builtin_bit_cast(bf16x2, __builtin_amdgcn_cvt_pk_bf16_f32(lo.z, lo.w));
  bf16x2 p2 = __builtin_bit_cast(bf16x2, __builtin_amdgcn_cvt_pk_bf16_f32(hi.x, hi.y));
  bf16x2 p3 = __builtin_bit_cast(bf16x2, __builtin_amdgcn_cvt_pk_bf16_f32(hi.z, hi.w));
  r[0] = p0[0]; r[1] = p0[1]; r[2] = p1[0]; r[3] = p1[1];
  r[4] = p2[0]; r[5] = p2[1]; r[6] = p3[0]; r[7] = p3[1];
#else
  u16x8 t;
  t[0] = f2bf(lo.x); t[1] = f2bf(lo.y); t[2] = f2bf(lo.z); t[3] = f2bf(lo.w);
  t[4] = f2bf(hi.x); t[5] = f2bf(hi.y); t[6] = f2bf(hi.z); t[7] = f2bf(hi.w);
  r = __builtin_bit_cast(bf16x8, t);
#endif
  return r;
}

__device__ __forceinline__ void gld16(const unsigned short* g, unsigned short* l) {
  __builtin_amdgcn_global_load_lds(
      (const __attribute__((address_space(1))) unsigned int*)(g),
      (__attribute__((address_space(3))) unsigned int*)(l), 16, 0, 0);
}

// Prep: LDS-tiled transpose of w into wt layout [mat][j][k0][fq][e][dq] (bf16).
// Block 256 (last) writes the cu_out prefix tail.
__global__ void prep_kernel(const float* __restrict__ wk, const float* __restrict__ wv,
                            unsigned short* __restrict__ wt,
                            const int* __restrict__ cu, int num_seqs,
                            float* __restrict__ tail) {
  const int bx = blockIdx.x;
  if (bx == 2 * BS * 4) {
    if (threadIdx.x == 0) {
      int acc = 0;
      tail[0] = 0.0f;
      for (int b = 0; b < num_seqs; ++b) {
        int n = cu[b + 1] - cu[b];
        acc += (n - BS) / STRIDE;
        tail[b + 1] = (float)acc;
      }
    }
    return;
  }
  const int mat = bx >> 7;
  const int j   = (bx >> 2) & 31;
  const int k0  = bx & 3;
  const float* __restrict__ w =
      (mat ? wv : wk) + (size_t)j * (HD * HD) + (size_t)k0 * 32 * HD;
  __shared__ unsigned short tile[32][HD];
  const int t = threadIdx.x;
  const int r = t >> 3, c = (t & 7) * 16;
#pragma unroll
  for (int i = 0; i < 16; i += 4) {
    float4 f = *(const float4*)(w + r * HD + c + i);
    tile[r][c + i + 0] = f2bf(f.x);
    tile[r][c + i + 1] = f2bf(f.y);
    tile[r][c + i + 2] = f2bf(f.z);
    tile[r][c + i + 3] = f2bf(f.w);
  }
  __syncthreads();
  unsigned short* dst =
      wt + (size_t)mat * (BS * HD * HD) + (size_t)j * 16384 + k0 * 4096;
#pragma unroll
  for (int it = 0; it < 2; ++it) {
    int fi = t + it * 256;      // 0..511 over (fq, e)
    int fq = fi >> 7, e = fi & 127;
    u16x8 fr;
#pragma unroll
    for (int dq = 0; dq < 8; ++dq) fr[dq] = tile[fq * 8 + dq][e];
    *(u16x8*)(dst + fq * 1024 + e * 8) = fr;
  }
}

// Main GEMM, v7: j-outer loop, 32 big steps. Block = 16 consecutive output
// windows of ONE sequence (64 m-rows) x full n=128; 4 waves of 16m x 128n.
// Per step: stage wt[j] (32 KB) into double-buffered LDS (m97-canonical:
// stage-next, compute-cur, ONE __syncthreads), waves read 32 KB of fresh
// sequential A per block. The 32 KB HBM quantum per interval makes service
// time (~3.2K cy at saturated per-CU share) dominate latency/drain costs:
// back-to-back service periods = full bandwidth by construction.
// 512 blocks exactly = 2/CU. K-order (j asc, k0 asc) -> bit-identical output.
__global__ __launch_bounds__(256, 2) void kvc_gemm(
    const float* __restrict__ kp, const float* __restrict__ vp,
    const unsigned short* __restrict__ wt, const int* __restrict__ cu,
    float* __restrict__ out, long out_half, int M_total, int num_seqs) {

  __shared__ __align__(16) unsigned short Bs0[16384];   // 32 KB: wt[j] slice
  __shared__ __align__(16) unsigned short Bs1[16384];   // 32 KB

  const int mat = blockIdx.y;
  const float* __restrict__ x = mat ? vp : kp;
  const unsigned short* __restrict__ wmat = wt + (size_t)mat * (BS * HD * HD);
  float* __restrict__ outp = out + (size_t)mat * out_half;

  // Block scan: find (seq, first output window o0, out prefix ob).
  const int bx = blockIdx.x;
  int o0 = -1, ob = 0, ol_b = 0, tb0 = 0;
  {
    int accB = 0, accO = 0;
    for (int b = 0; b < num_seqs; ++b) {
      int c0 = cu[b], c1 = cu[b + 1];
      int ol = (c1 - c0 - BS) / STRIDE;
      int nb = (ol + 15) >> 4;
      if (o0 < 0 && bx < accB + nb) {
        o0 = (bx - accB) * 16; ob = accO; ol_b = ol; tb0 = c0;
      }
      accB += nb; accO += ol;
    }
  }
  if (o0 < 0) return;   // overprovisioned grid tail

  const int tid = threadIdx.x, wid = tid >> 6, lane = tid & 63;
  const int fl = lane & 15, fq = lane >> 4;

  // This lane's m-row: local window orow (clamped for loads), head h.
  const int orow = o0 + wid * 4 + (fl >> 2);
  const int ocl = orow < ol_b ? orow : ol_b - 1;
  const int h = fl & 3;
  // Token for step j is (tb0 + ocl*16 + j): A advances by j*NH*HD floats.
  const float* __restrict__ arow =
      x + ((size_t)((tb0 + ocl * STRIDE) * NH + h)) * HD + fq * 8;

  floatx4 acc[8];
#pragma unroll
  for (int ni = 0; ni < 8; ++ni) acc[ni] = (floatx4){0.f, 0.f, 0.f, 0.f};

  float4 a0[8], a1[8];   // A parity regs (static indices)

  // Stage wt[j] slice (32 KB contiguous) into BW: 8 gld16/thread, linear.
#define BSTAGE(J, BW)                                                       \
  {                                                                         \
    const unsigned short* s_ = wmat + (size_t)(J) * 16384 + tid * 8;        \
    _Pragma("unroll") for (int i_ = 0; i_ < 8; ++i_)                        \
        gld16(s_ + i_ * 2048, &BW[i_ * 2048 + tid * 8]);                    \
  }

  // Load A for step JN into parity array AN: 8 dwordx4/lane (128 B/lane).
#define ALOAD(JN, AN)                                                       \
  {                                                                         \
    const float* ar_ = arow + (size_t)(JN) * (NH * HD);                     \
    _Pragma("unroll") for (int k_ = 0; k_ < 4; ++k_) {                      \
      AN[2 * k_]     = *(const float4*)(ar_ + k_ * 32);                     \
      AN[2 * k_ + 1] = *(const float4*)(ar_ + k_ * 32 + 4);                 \
    }                                                                       \
  }

  // 32 MFMA from buffer BR with A parity AN: k0 asc, ni inner (v1 order).
#define COMPUTE(AN, BR)                                                     \
  {                                                                         \
    bf16x8 af_[4];                                                          \
    _Pragma("unroll") for (int k_ = 0; k_ < 4; ++k_)                        \
        af_[k_] = cvt8(AN[2 * k_], AN[2 * k_ + 1]);                         \
    _Pragma("unroll") for (int k_ = 0; k_ < 4; ++k_) {                      \
      _Pragma("unroll") for (int ni_ = 0; ni_ < 8; ++ni_) {                 \
        bf16x8 bf_ = *(const bf16x8*)&BR[k_ * 4096 + fq * 1024 +            \
                                         (ni_ * 16 + fl) * 8];              \
        acc[ni_] = __builtin_amdgcn_mfma_f32_16x16x32_bf16(                 \
            af_[k_], bf_, acc[ni_], 0, 0, 0);                               \
      }                                                                     \
    }                                                                       \
  }

  // Prologue: stage slice 0, load A(0), one barrier to make Bs0 ready.
  BSTAGE(0, Bs0);
  ALOAD(0, a0);
  __syncthreads();

  // m97-canonical loop, unrolled x2 for register parity. One barrier/step.
  for (int j = 0; j < BS; j += 2) {
    // step j (even): stage j+1 -> Bs1/a1, compute from Bs0/a0.
    BSTAGE(j + 1, Bs1);
    ALOAD(j + 1, a1);
    __builtin_amdgcn_sched_barrier(0);   // loads issue before MFMA cluster
    COMPUTE(a0, Bs0);
    __syncthreads();                     // drains stage(j+1); readers done
    // step j+1 (odd): stage j+2 -> Bs0/a0, compute from Bs1/a1.
    if (j + 2 < BS) {
      BSTAGE(j + 2, Bs0);
      ALOAD(j + 2, a0);
    }
    __builtin_amdgcn_sched_barrier(0);
    COMPUTE(a1, Bs1);
    __syncthreads();
  }

#undef COMPUTE
#undef ALOAD
#undef BSTAGE

  // C/D: col = ni*16+fl, row = fq*4 + r -> (window = row>>2, head = row&3).
#pragma unroll
  for (int ni = 0; ni < 8; ++ni) {
#pragma unroll
    for (int r = 0; r < 4; ++r) {
      const int row = fq * 4 + r;
      const int ow = o0 + wid * 4 + (row >> 2);
      if (ow < ol_b) {
        const size_t mg = ((size_t)(ob + ow) * NH + (row & 3));
        outp[mg * HD + ni * 16 + fl] = acc[ni][r];
      }
    }
  }
}

// Fallback path if ws is too small for the weight transpose.
__global__ void tail_kernel(const int* __restrict__ cu, int num_seqs,
                            float* __restrict__ tail) {
  if (threadIdx.x == 0) {
    int acc = 0;
    tail[0] = 0.0f;
    for (int b = 0; b < num_seqs; ++b) {
      int n = cu[b + 1] - cu[b];
      acc += (n - BS) / STRIDE;
      tail[b + 1] = (float)acc;
    }
  }
}

__global__ void kvc_naive(const float* __restrict__ kp, const float* __restrict__ vp,
                          const float* __restrict__ wk, const float* __restrict__ wv,
                          const int* __restrict__ cu, int num_seqs,
                          float* __restrict__ out, long out_half) {
  int o = blockIdx.x, h = blockIdx.y, mat = blockIdx.z;
  int e = threadIdx.x;
  int acc = 0, base = -1;
  for (int b = 0; b < num_seqs; ++b) {
    int n = cu[b + 1] - cu[b];
    int ol = (n - BS) / STRIDE;
    if (o < acc + ol) { base = cu[b] + (o - acc) * STRIDE; break; }
    acc += ol;
  }
  if (base < 0) return;
  const float* x = mat ? vp : kp;
  const float* w = mat ? wv : wk;
  float s = 0.f;
  for (int j = 0; j < BS; ++j)
    for (int d = 0; d < HD; ++d)
      s += x[(size_t)(base + j) * (NH * HD) + h * HD + d] * w[(j * HD + d) * HD + e];
  out[(size_t)mat * out_half + ((size_t)o * NH + h) * HD + e] = s;
}

extern "C" void kernel_launch(void* const* d_in, const int* in_sizes, int n_in,
                              void* d_out, int out_size, void* d_ws, size_t ws_size,
                              hipStream_t stream) {
  const float* kp = (const float*)d_in[0];
  const float* vp = (const float*)d_in[1];
  const float* wk = (const float*)d_in[2];
  const float* wv = (const float*)d_in[3];
  const int* cu = (const int*)d_in[4];
  const int num_seqs = in_sizes[4] - 1;
  float* out = (float*)d_out;

  const long total_out = ((long)out_size - (num_seqs + 1)) / (2L * NH * HD);
  const long out_half = total_out * NH * HD;
  const int M_total = (int)(total_out * NH);
  float* tail = out + 2 * out_half;

  const size_t need_ws = (size_t)2 * BS * HD * HD * sizeof(unsigned short);
  if (ws_size >= need_ws) {
    unsigned short* wt = (unsigned short*)d_ws;
    prep_kernel<<<2 * BS * 4 + 1, 256, 0, stream>>>(wk, wv, wt, cu, num_seqs, tail);
    // Per-seq blocks of 16 windows; overprovision (exact count needs device cu).
    const int gx = (int)(total_out / 16) + num_seqs;
    dim3 grid(gx, 2);
    kvc_gemm<<<grid, 256, 0, stream>>>(kp, vp, wt, cu, out, out_half, M_total,
                                       num_seqs);
  } else {
    tail_kernel<<<1, 64, 0, stream>>>(cu, num_seqs, tail);
    dim3 grid((unsigned)total_out, NH, 2);
    kvc_naive<<<grid, HD, 0, stream>>>(kp, vp, wk, wv, cu, num_seqs, out, out_half);
  }
}